// Round 4
// baseline (1035.274 us; speedup 1.0000x reference)
//
#include <hip/hip_runtime.h>
#include <stdint.h>

#define T_CTX 1024
#define DM 64
#define NH 2
#define HD 32
#define DFF 256
#define NVOCAB 8192
#define NBLOCKS 512

typedef int v4i __attribute__((ext_vector_type(4)));

__device__ __forceinline__ int clampi(int v, int lo, int hi){ return v<lo?lo:(v>hi?hi:v); }
__device__ __forceinline__ int wrap8(int v){ return ((v + 128) & 255) - 128; }
__device__ __forceinline__ int sdot4(int a, int b, int c){ return __builtin_amdgcn_sdot4(a, b, c, false); }

__device__ __forceinline__ int wave_reduce_add(int v){
  #pragma unroll
  for (int off = 1; off < 64; off <<= 1) v += __shfl_xor(v, off, 64);
  return v;
}
__device__ __forceinline__ int wave_reduce_max(int v){
  #pragma unroll
  for (int off = 1; off < 64; off <<= 1){ int o = __shfl_xor(v, off, 64); v = o > v ? o : v; }
  return v;
}

// device-scope sense-reversing grid barrier; agent-scope acq/rel gives cross-XCD
// L2 writeback/invalidate on gfx950. All NBLOCKS blocks are co-resident
// (__launch_bounds__(256,2) => 2 blocks/CU * 256 CU = 512 = grid).
__device__ __forceinline__ void gbar(int* cnt, int* gen){
  __syncthreads();                     // drains vmcnt(0): this block's stores are in L2
  if (threadIdx.x == 0) {
    int g = __hip_atomic_load(gen, __ATOMIC_RELAXED, __HIP_MEMORY_SCOPE_AGENT);
    int prev = __hip_atomic_fetch_add(cnt, 1, __ATOMIC_ACQ_REL, __HIP_MEMORY_SCOPE_AGENT);
    if (prev == NBLOCKS - 1) {
      __hip_atomic_store(cnt, 0, __ATOMIC_RELAXED, __HIP_MEMORY_SCOPE_AGENT);
      __hip_atomic_store(gen, g + 1, __ATOMIC_RELEASE, __HIP_MEMORY_SCOPE_AGENT);
    } else {
      while (__hip_atomic_load(gen, __ATOMIC_ACQUIRE, __HIP_MEMORY_SCOPE_AGENT) == g) {
        __builtin_amdgcn_s_sleep(8);
      }
    }
  }
  __syncthreads();
}

// rmsnorm_hw forward: exact integer pipeline; lane == channel (wave64 == DM)
__device__ __forceinline__ int rmsnorm_one(int xv, int g){
  int ss  = wave_reduce_add(xv * xv);
  int ms  = ss >> 6;                 // /64 == /d_model
  int lut = ms >> 6; if (lut > 255) lut = 255;
  int bc  = lut * 64 + 32;           // >= 32, so max(.,1) vacuous
  int inv = (int)__builtin_rint(16384.0 / __builtin_sqrt((double)bc)); // <= 2897 < 16383
  int p1  = (xv * inv) >> 8;         // arithmetic shift == floor
  int y   = (p1 * g) >> 10;
  return clampi(y, -128, 127);
}

// norm + QKV projections for one token; myS = 256B wave-private LDS; V stored transposed
__device__ __forceinline__ void do_qkv(int t, int xv, int L, int lane, int8_t* myS,
    const int8_t* wt, const int16_t* gq, int8_t* qA, int8_t* kA, int8_t* vT)
{
  int h = rmsnorm_one(xv, (int)gq[L*DM + lane]);
  myS[lane] = (int8_t)h;
  __syncthreads();
  const int8_t* wtL = wt + L*49152;
  const int* h4 = (const int*)myS;
  const int* wq = (const int*)(wtL + 0);
  const int* wk = (const int*)(wtL + 4096);
  const int* wv = (const int*)(wtL + 8192);
  int b = t >> 10, s = t & (T_CTX - 1);
  int hh = lane >> 5, d = lane & 31;
  int bhh = b*NH + hh;
  int accq = 0, acck = 0, accv = 0;
  #pragma unroll
  for (int i = 0; i < 16; i++) {
    int hv = h4[i];
    accq = sdot4(hv, wq[lane*16 + i], accq);
    acck = sdot4(hv, wk[lane*16 + i], acck);
    accv = sdot4(hv, wv[lane*16 + i], accv);
  }
  qA[(bhh*T_CTX + s)*HD + d] = (int8_t)clampi(accq >> 6, -128, 127);
  kA[(bhh*T_CTX + s)*HD + d] = (int8_t)clampi(acck >> 6, -128, 127);
  vT[(bhh*HD + d)*T_CTX + s] = (int8_t)clampi(accv >> 6, -128, 127);
}

// attention for 4 q-rows per wave; V^T staged in block LDS; probs per-wave LDS row
__device__ __forceinline__ void attn_phase(int bid, int w, int lane,
    const int8_t* __restrict__ qA, const int8_t* __restrict__ kA,
    const int8_t* __restrict__ vT, int8_t* __restrict__ aOut, char* smemc)
{
  int bh = bid & 7, qgrp = bid >> 3;     // 8 bh groups x 64 q-groups
  int b = bh >> 1, h = bh & 1;
  const int8_t* qBase = qA + bh*(T_CTX*HD);
  const int8_t* kBase = kA + bh*(T_CTX*HD);
  const int8_t* vTbh  = vT + bh*(HD*T_CTX);
  int* vt32 = (int*)smemc;               // [32][257] ints, stride 257 kills conflicts
  #pragma unroll
  for (int r = 0; r < 8; r++) {
    int d = r*4 + w;
    int4 v = *(const int4*)(vTbh + d*T_CTX + lane*16);
    int* dst = vt32 + d*257 + lane*4;
    dst[0] = v.x; dst[1] = v.y; dst[2] = v.z; dst[3] = v.w;
  }
  __syncthreads();
  uint8_t* spb = (uint8_t*)(smemc + 32896 + w*1024);
  const int* spw = (const int*)spb;
  int dg = lane & 7, kc = lane >> 3;
  const int* vr0 = vt32 + (dg*4 + 0)*257;
  const int* vr1 = vt32 + (dg*4 + 1)*257;
  const int* vr2 = vt32 + (dg*4 + 2)*257;
  const int* vr3 = vt32 + (dg*4 + 3)*257;
  #pragma unroll
  for (int ri = 0; ri < 4; ri++) {
    int i = w + ri*4;                    // 0..15, balanced across waves
    int qi = i*64 + qgrp;
    // ---- QK^T row ----
    const int4* qr = (const int4*)(qBase + qi*HD);
    int4 qa = qr[0], qb = qr[1];
    int sc[16];
    int mloc = -(1 << 30);
    #pragma unroll
    for (int j = 0; j < 16; j++) {
      int k = lane + j*64;
      int s;
      if (k <= qi) {
        const int4* kr = (const int4*)(kBase + k*HD);
        int4 ka = kr[0], kb = kr[1];
        int d0 = 0, d1 = 0;
        d0 = sdot4(qa.x, ka.x, d0); d1 = sdot4(qa.y, ka.y, d1);
        d0 = sdot4(qa.z, ka.z, d0); d1 = sdot4(qa.w, ka.w, d1);
        d0 = sdot4(qb.x, kb.x, d0); d1 = sdot4(qb.y, kb.y, d1);
        d0 = sdot4(qb.z, kb.z, d0); d1 = sdot4(qb.w, kb.w, d1);
        s = ((d0 + d1) * 45) >> 8;       // floor; diag >=0 so mask never wins max
      } else s = -(1 << 30);
      sc[j] = s; if (s > mloc) mloc = s;
    }
    int m = wave_reduce_max(mloc);
    int ssum = 0;
    #pragma unroll
    for (int j = 0; j < 16; j++) {
      int k = lane + j*64;
      int e = 0;
      if (k <= qi) {
        int sh = sc[j] - m;              // <= 0
        e = (sh >= -3) ? (256 + sh*64)
          : (sh >= -8) ? (64 + (sh + 3)*11)
          : (sh >= -24) ? (sh + 24) : 0;
      }
      sc[j] = e; ssum += e;
    }
    int s0 = wave_reduce_add(ssum); if (s0 < 1) s0 = 1;
    float sf = (float)s0;
    #pragma unroll
    for (int j = 0; j < 16; j++) {
      int k = lane + j*64;
      int p = (int)__builtin_rintf((float)sc[j] / sf * 255.0f);  // 0 for k>qi
      spb[k] = (uint8_t)clampi(p, 0, 255);
    }
    __syncthreads();
    // ---- PV via packed sdot4: p = 2*(p>>1) + (p&1) ----
    int hi0=0, hi1=0, hi2=0, hi3=0, lo0=0, lo1=0, lo2=0, lo3=0;
    int cmax = qi >> 2;
    for (int c = kc; c <= cmax; c += 8) {
      int p4 = spw[c];
      int ph = (p4 >> 1) & 0x7f7f7f7f;
      int pl = p4 & 0x01010101;
      int v0 = vr0[c], v1 = vr1[c], v2 = vr2[c], v3 = vr3[c];
      hi0 = sdot4(ph, v0, hi0); lo0 = sdot4(pl, v0, lo0);
      hi1 = sdot4(ph, v1, hi1); lo1 = sdot4(pl, v1, lo1);
      hi2 = sdot4(ph, v2, hi2); lo2 = sdot4(pl, v2, lo2);
      hi3 = sdot4(ph, v3, hi3); lo3 = sdot4(pl, v3, lo3);
    }
    int a0 = 2*hi0 + lo0, a1 = 2*hi1 + lo1, a2 = 2*hi2 + lo2, a3 = 2*hi3 + lo3;
    #pragma unroll
    for (int off = 8; off < 64; off <<= 1) {
      a0 += __shfl_xor(a0, off, 64);
      a1 += __shfl_xor(a1, off, 64);
      a2 += __shfl_xor(a2, off, 64);
      a3 += __shfl_xor(a3, off, 64);
    }
    if (kc == 0) {
      int r0 = wrap8(a0 >> 8) & 255;
      int r1 = wrap8(a1 >> 8) & 255;
      int r2 = wrap8(a2 >> 8) & 255;
      int r3 = wrap8(a3 >> 8) & 255;
      int packed = r0 | (r1 << 8) | (r2 << 16) | (r3 << 24);
      *(int*)(aOut + (b*T_CTX + qi)*DM + h*HD + dg*4) = packed;
    }
    __syncthreads();   // keep spb write (next ri) after all waves' PV reads; uniform
  }
}

// post-layer: o-proj + residual + FFN + residual, then QKV(L+1) or final norm
__device__ __forceinline__ void post_phase(int gw, int w, int lane, int L,
    int8_t* x, const int8_t* __restrict__ aArr,
    int8_t* qA, int8_t* kA, int8_t* vT,
    const int8_t* __restrict__ wt, const int16_t* __restrict__ gq,
    int8_t* xf, char* smemc)
{
  int8_t* myS = (int8_t*)smemc + w*DFF;
  const int8_t* wtL = wt + L*49152;
  for (int tt = 0; tt < 2; tt++) {
    int t = gw*2 + tt;
    int xv = (int)x[t*DM + lane];
    myS[lane] = aArr[t*DM + lane];
    __syncthreads();
    { // o-projection
      const int* a4 = (const int*)myS;
      const int* wo = (const int*)(wtL + 12288);
      int acc = 0;
      #pragma unroll
      for (int i = 0; i < 16; i++) acc = sdot4(a4[i], wo[lane*16 + i], acc);
      xv = wrap8(xv + clampi(acc >> 6, -128, 127));
    }
    __syncthreads();
    int h2 = rmsnorm_one(xv, (int)gq[(4 + L)*DM + lane]);
    myS[lane] = (int8_t)h2;
    __syncthreads();
    int uv[4];
    { // up projection (256 outs, 4/lane) + relu
      const int* h4 = (const int*)myS;
      const int* wu = (const int*)(wtL + 16384);
      #pragma unroll
      for (int jj = 0; jj < 4; jj++) {
        int acc = 0;
        #pragma unroll
        for (int i = 0; i < 16; i++) acc = sdot4(h4[i], wu[(jj*64 + lane)*16 + i], acc);
        int u = clampi(acc >> 6, -128, 127);
        uv[jj] = u < 0 ? 0 : u;
      }
    }
    __syncthreads();
    #pragma unroll
    for (int jj = 0; jj < 4; jj++) myS[jj*64 + lane] = (int8_t)uv[jj];
    __syncthreads();
    { // down projection
      const int* u4 = (const int*)myS;
      const int* wd = (const int*)(wtL + 32768);
      int acc = 0;
      #pragma unroll
      for (int i = 0; i < 64; i++) acc = sdot4(u4[i], wd[lane*64 + i], acc);
      xv = wrap8(xv + clampi(acc >> 6, -128, 127));
    }
    x[t*DM + lane] = (int8_t)xv;
    __syncthreads();
    if (L < 3) {
      do_qkv(t, xv, L + 1, lane, myS, wt, gq, qA, kA, vT);
    } else {
      int h = rmsnorm_one(xv, (int)gq[8*DM + lane]);
      xf[t*DM + lane] = (int8_t)h;
    }
    __syncthreads();
  }
}

// ---------------- the megakernel: prep + embed + 4 layers, hand-rolled grid barrier ----------------
__global__ __launch_bounds__(256, 2) void mega(
    const int* __restrict__ tokens, const float* __restrict__ tok_emb, const float* __restrict__ pos_emb,
    const float* __restrict__ anw, const float* __restrict__ qw, const float* __restrict__ kw,
    const float* __restrict__ vw, const float* __restrict__ ow, const float* __restrict__ fnw,
    const float* __restrict__ uw, const float* __restrict__ dw, const float* __restrict__ finw,
    int8_t* x, int8_t* a, int8_t* qA, int8_t* kA, int8_t* vT,
    int8_t* wt, int16_t* gq, int8_t* elo, int8_t* ehi, int8_t* xf,
    int* bar_cnt, int* bar_gen)
{
  __shared__ __align__(16) char smemc[36992];  // attn: V^T 32896 + probs 4096; token: 1KB; prep: 2KB
  int tid = threadIdx.x, bid = blockIdx.x;
  int w = tid >> 6, lane = tid & 63;
  int gw = bid*4 + w;                          // 0..2047

  // ---- P0: weight ternarize + gammas + emb split + embed ----
  if (bid < 24) {
    int layer = bid / 6, kind = bid % 6;
    const float* src; int n; int off;
    switch (kind) {
      case 0:  src = qw + layer*4096;  n = 4096;  off = 0;     break;
      case 1:  src = kw + layer*4096;  n = 4096;  off = 4096;  break;
      case 2:  src = vw + layer*4096;  n = 4096;  off = 8192;  break;
      case 3:  src = ow + layer*4096;  n = 4096;  off = 12288; break;
      case 4:  src = uw + layer*16384; n = 16384; off = 16384; break;
      default: src = dw + layer*16384; n = 16384; off = 32768; break;
    }
    double* sred = (double*)smemc;
    double s = 0.0;
    for (int i = tid; i < n; i += 256) s += (double)__builtin_fabsf(src[i]);
    sred[tid] = s; __syncthreads();
    for (int st = 128; st > 0; st >>= 1){ if (tid < st) sred[tid] += sred[tid + st]; __syncthreads(); }
    float fs = (float)(sred[0] / (double)n);
    if (fs < 1e-5f) fs = 1e-5f;
    int8_t* dst = wt + layer*49152 + off;
    for (int i = tid; i < n; i += 256) {
      int tq = (int)__builtin_rintf(src[i] / fs);
      dst[i] = (int8_t)clampi(tq, -1, 1);
    }
  } else if (bid == 24) {
    for (int i = tid; i < 576; i += 256) {
      int norm = i >> 6, c = i & 63;
      const float* wsrc = (norm < 4) ? (anw + norm*64) : (norm < 8) ? (fnw + (norm-4)*64) : finw;
      float wv = wsrc[c];
      float wc = wv < -2.0f ? -2.0f : (wv > 2.0f ? 2.0f : wv);
      gq[i] = (int16_t)clampi((int)__builtin_rintf(wc * 1024.0f), -32768, 32767);
    }
  }
  for (int i = bid*256 + tid; i < NVOCAB*DM; i += NBLOCKS*256) {
    int e  = clampi((int)__builtin_rintf(tok_emb[i] * 1024.0f), -32768, 32767);
    int l  = ((e + 128) & 255) - 128;
    int hh = (e - l) >> 8;
    if (hh > 127) hh = 127;
    elo[i] = (int8_t)l; ehi[i] = (int8_t)hh;
  }
  for (int i = bid*256 + tid; i < 4096*DM; i += NBLOCKS*256) {
    int t = i >> 6, c = i & 63;
    int tok = tokens[t];
    int s = t & (T_CTX - 1);
    int tq = clampi((int)__builtin_rintf(tok_emb[tok*DM + c] * 1024.0f), -32768, 32767);
    int pq = clampi((int)__builtin_rintf(pos_emb[s*DM + c] * 1024.0f), -32768, 32767);
    x[i] = (int8_t)wrap8((tq + pq) >> 3);
  }
  gbar(bar_cnt, bar_gen);

  // ---- QKV for layer 0 ----
  {
    int8_t* myS = (int8_t*)smemc + w*DFF;
    for (int tt = 0; tt < 2; tt++) {
      int t = gw*2 + tt;
      int xv = (int)x[t*DM + lane];
      do_qkv(t, xv, 0, lane, myS, wt, gq, qA, kA, vT);
      __syncthreads();
    }
  }
  gbar(bar_cnt, bar_gen);

  // ---- 4 layers ----
  for (int L = 0; L < 4; L++) {
    attn_phase(bid, w, lane, qA, kA, vT, a, smemc);
    gbar(bar_cnt, bar_gen);
    post_phase(gw, w, lane, L, x, a, qA, kA, vT, wt, gq, xf, smemc);
    if (L < 3) gbar(bar_cnt, bar_gen);
  }
}

// ---------------- logits: xf[4096x64] int8 x emb(hi/lo int8)[8192x64]^T via i8 MFMA ----------------
__global__ __launch_bounds__(256) void logits_kernel(
    const int8_t* __restrict__ xf, const int8_t* __restrict__ elo, const int8_t* __restrict__ ehi,
    float* __restrict__ out)
{
  int w = threadIdx.x >> 6, lane = threadIdx.x & 63;
  int m = lane & 15, quad = lane >> 4;
  int tokBase = blockIdx.y * 64 + w * 16;
  v4i A = *(const v4i*)(xf + (tokBase + m)*DM + quad*16);  // A[m=lane&15][k=quad*16+j]
  #pragma unroll
  for (int tile = 0; tile < 8; tile++) {
    int vocBase = blockIdx.x * 128 + tile * 16;
    v4i Blo = *(const v4i*)(elo + (vocBase + m)*DM + quad*16);
    v4i Bhi = *(const v4i*)(ehi + (vocBase + m)*DM + quad*16);
    v4i zero = {0, 0, 0, 0};
    v4i dLo = __builtin_amdgcn_mfma_i32_16x16x64_i8(A, Blo, zero, 0, 0, 0);
    v4i dHi = __builtin_amdgcn_mfma_i32_16x16x64_i8(A, Bhi, zero, 0, 0, 0);
    #pragma unroll
    for (int r = 0; r < 4; r++) {
      int val = dLo[r] + (dHi[r] << 8);                     // dot(x, 256*hi + lo), exact int32
      int row = tokBase + quad*4 + r;                       // C/D: row=(lane>>4)*4+reg
      int col = vocBase + m;                                // col=lane&15
      out[row*NVOCAB + col] = (float)val * 1.220703125e-4f; // * 2^-13 == D^-0.5/1024
    }
  }
}

extern "C" void kernel_launch(void* const* d_in, const int* in_sizes, int n_in,
                              void* d_out, int out_size, void* d_ws, size_t ws_size,
                              hipStream_t stream)
{
  const int*   tokens  = (const int*)d_in[0];
  const float* tok_emb = (const float*)d_in[1];
  const float* pos_emb = (const float*)d_in[2];
  const float* attn_nw = (const float*)d_in[3];
  const float* q_w     = (const float*)d_in[4];
  const float* k_w     = (const float*)d_in[5];
  const float* v_w     = (const float*)d_in[6];
  const float* o_w     = (const float*)d_in[7];
  const float* ff_nw   = (const float*)d_in[8];
  const float* up_w    = (const float*)d_in[9];
  const float* dn_w    = (const float*)d_in[10];
  const float* fin_nw  = (const float*)d_in[11];
  float* out = (float*)d_out;
  char* ws = (char*)d_ws;

  int8_t*  x   = (int8_t*)(ws + 0);        // 4096*64
  int8_t*  a   = (int8_t*)(ws + 262144);   // 4096*64 attn output (token-major)
  int8_t*  qA  = (int8_t*)(ws + 524288);   // [b][h][t][d]
  int8_t*  kA  = (int8_t*)(ws + 786432);   // [b][h][t][d]
  int8_t*  vT  = (int8_t*)(ws + 1048576);  // [b][h][d][t]  (transposed V)
  int8_t*  wt  = (int8_t*)(ws + 1310720);  // 4 layers * 49152 ternary weights
  int8_t*  elo = (int8_t*)(ws + 1507328);  // 8192*64
  int8_t*  ehi = (int8_t*)(ws + 2031616);  // 8192*64
  int16_t* gq  = (int16_t*)(ws + 2555904); // 9*64
  int8_t*  xf  = (int8_t*)(ws + 2560000);  // 4096*64
  int*     bar = (int*)(ws + 2822144);     // [cnt, gen]

  hipMemsetAsync(bar, 0, 2*sizeof(int), stream);
  mega<<<NBLOCKS, 256, 0, stream>>>(
      tokens, tok_emb, pos_emb, attn_nw, q_w, k_w, v_w, o_w, ff_nw, up_w, dn_w, fin_nw,
      x, a, qA, kA, vT, wt, gq, elo, ehi, xf, bar, bar + 1);
  logits_kernel<<<dim3(64, 64), 256, 0, stream>>>(xf, elo, ehi, out);
}

// Round 5
// 788.646 us; speedup vs baseline: 1.3127x; 1.3127x over previous
//
#include <hip/hip_runtime.h>
#include <stdint.h>

#define T_CTX 1024
#define DM 64
#define NH 2
#define HD 32
#define DFF 256
#define NVOCAB 8192
#define NBLOCKS 1024
#define WAIT_LGKM 0xC07F   // s_waitcnt lgkmcnt(0)

typedef int v4i __attribute__((ext_vector_type(4)));

__device__ __forceinline__ int clampi(int v, int lo, int hi){ return v<lo?lo:(v>hi?hi:v); }
__device__ __forceinline__ int wrap8(int v){ return ((v + 128) & 255) - 128; }
__device__ __forceinline__ int sdot4(int a, int b, int c){ return __builtin_amdgcn_sdot4(a, b, c, false); }

__device__ __forceinline__ int wave_reduce_add(int v){
  #pragma unroll
  for (int off = 1; off < 64; off <<= 1) v += __shfl_xor(v, off, 64);
  return v;
}
__device__ __forceinline__ int wave_reduce_max(int v){
  #pragma unroll
  for (int off = 1; off < 64; off <<= 1){ int o = __shfl_xor(v, off, 64); v = o > v ? o : v; }
  return v;
}

// Grid barrier, thrash-free: RELAXED polls/arrivals (no per-op cache maintenance),
// ONE threadfence pair per block per barrier. Hierarchical: 8 group counters
// (128 blocks each, 128B-padded lines) -> master -> gen. RELEASE on publish edges
// orders the counter resets ahead of the next-barrier arrivals.
__device__ __forceinline__ void gbar(int* bar, int bid){
  __syncthreads();
  if (threadIdx.x == 0) {
    __threadfence();                   // wbl2: this block's stores -> agent-visible
    int* gen = bar + 320;
    int g = __hip_atomic_load(gen, __ATOMIC_RELAXED, __HIP_MEMORY_SCOPE_AGENT);
    int* grp = bar + (bid & 7) * 32;
    int prev = __hip_atomic_fetch_add(grp, 1, __ATOMIC_RELAXED, __HIP_MEMORY_SCOPE_AGENT);
    if (prev == 127) {
      __hip_atomic_store(grp, 0, __ATOMIC_RELAXED, __HIP_MEMORY_SCOPE_AGENT);
      int* mst = bar + 288;
      int p2 = __hip_atomic_fetch_add(mst, 1, __ATOMIC_RELEASE, __HIP_MEMORY_SCOPE_AGENT);
      if (p2 == 7) {
        __hip_atomic_store(mst, 0, __ATOMIC_RELAXED, __HIP_MEMORY_SCOPE_AGENT);
        __hip_atomic_store(gen, g + 1, __ATOMIC_RELEASE, __HIP_MEMORY_SCOPE_AGENT);
      }
    }
    int iters = 0;
    while (__hip_atomic_load(gen, __ATOMIC_RELAXED, __HIP_MEMORY_SCOPE_AGENT) == g
           && iters < (1 << 20)) { __builtin_amdgcn_s_sleep(2); ++iters; }
    __threadfence();                   // inv: subsequent reads bypass stale cache
  }
  __syncthreads();
}

// rmsnorm_hw forward: exact integer pipeline; lane == channel (wave64 == DM)
__device__ __forceinline__ int rmsnorm_one(int xv, int g){
  int ss  = wave_reduce_add(xv * xv);
  int ms  = ss >> 6;                 // /64 == /d_model
  int lut = ms >> 6; if (lut > 255) lut = 255;
  int bc  = lut * 64 + 32;           // >= 32, so max(.,1) vacuous
  int inv = (int)__builtin_rint(16384.0 / __builtin_sqrt((double)bc)); // <= 2897 < 16383
  int p1  = (xv * inv) >> 8;         // arithmetic shift == floor
  int y   = (p1 * g) >> 10;
  return clampi(y, -128, 127);
}

// norm + QKV projections for one token; myS = 256B wave-private LDS; V stored transposed
__device__ __forceinline__ void do_qkv(int t, int xv, int L, int lane, int8_t* myS,
    const int8_t* wt, const int16_t* gq, int8_t* qA, int8_t* kA, int8_t* vT)
{
  int h = rmsnorm_one(xv, (int)gq[L*DM + lane]);
  myS[lane] = (int8_t)h;
  __syncthreads();
  const int8_t* wtL = wt + L*49152;
  const int* h4 = (const int*)myS;
  const int* wq = (const int*)(wtL + 0);
  const int* wk = (const int*)(wtL + 4096);
  const int* wv = (const int*)(wtL + 8192);
  int b = t >> 10, s = t & (T_CTX - 1);
  int hh = lane >> 5, d = lane & 31;
  int bhh = b*NH + hh;
  int accq = 0, acck = 0, accv = 0;
  #pragma unroll
  for (int i = 0; i < 16; i++) {
    int hv = h4[i];
    accq = sdot4(hv, wq[lane*16 + i], accq);
    acck = sdot4(hv, wk[lane*16 + i], acck);
    accv = sdot4(hv, wv[lane*16 + i], accv);
  }
  qA[(bhh*T_CTX + s)*HD + d] = (int8_t)clampi(accq >> 6, -128, 127);
  kA[(bhh*T_CTX + s)*HD + d] = (int8_t)clampi(acck >> 6, -128, 127);
  vT[(bhh*HD + d)*T_CTX + s] = (int8_t)clampi(accv >> 6, -128, 127);
}

// attention: 2 balanced q-rows per wave (i in {w, 7-w}); V^T staged in block LDS
__device__ __forceinline__ void attn_phase(int bid, int w, int lane,
    const int8_t* __restrict__ qA, const int8_t* __restrict__ kA,
    const int8_t* __restrict__ vT, int8_t* __restrict__ aOut, char* smemc)
{
  int bh = bid & 7, qgrp = bid >> 3;     // 8 bh groups x 128 q-groups
  int b = bh >> 1, h = bh & 1;
  const int8_t* qBase = qA + bh*(T_CTX*HD);
  const int8_t* kBase = kA + bh*(T_CTX*HD);
  const int8_t* vTbh  = vT + bh*(HD*T_CTX);
  int* vt32 = (int*)smemc;               // [32][257] ints, stride 257 kills conflicts
  #pragma unroll
  for (int r = 0; r < 8; r++) {
    int d = r*4 + w;
    int4 v = *(const int4*)(vTbh + d*T_CTX + lane*16);
    int* dst = vt32 + d*257 + lane*4;
    dst[0] = v.x; dst[1] = v.y; dst[2] = v.z; dst[3] = v.w;
  }
  __syncthreads();
  uint8_t* spb = (uint8_t*)(smemc + 32896 + w*1024);  // wave-private prob row
  const int* spw = (const int*)spb;
  int dg = lane & 7, kc = lane >> 3;
  const int* vr0 = vt32 + (dg*4 + 0)*257;
  const int* vr1 = vt32 + (dg*4 + 1)*257;
  const int* vr2 = vt32 + (dg*4 + 2)*257;
  const int* vr3 = vt32 + (dg*4 + 3)*257;
  #pragma unroll
  for (int ri = 0; ri < 2; ri++) {
    int i = ri ? (7 - w) : w;            // pairs sum to 7: equal work per wave
    int qi = i*128 + qgrp;
    // ---- QK^T row ----
    const int4* qr = (const int4*)(qBase + qi*HD);
    int4 qa = qr[0], qb = qr[1];
    int sc[16];
    int mloc = -(1 << 30);
    #pragma unroll
    for (int j = 0; j < 16; j++) {
      int k = lane + j*64;
      int s;
      if (k <= qi) {
        const int4* kr = (const int4*)(kBase + k*HD);
        int4 ka = kr[0], kb = kr[1];
        int d0 = 0, d1 = 0;
        d0 = sdot4(qa.x, ka.x, d0); d1 = sdot4(qa.y, ka.y, d1);
        d0 = sdot4(qa.z, ka.z, d0); d1 = sdot4(qa.w, ka.w, d1);
        d0 = sdot4(qb.x, kb.x, d0); d1 = sdot4(qb.y, kb.y, d1);
        d0 = sdot4(qb.z, kb.z, d0); d1 = sdot4(qb.w, kb.w, d1);
        s = ((d0 + d1) * 45) >> 8;       // floor; diag >=0 so mask never wins max
      } else s = -(1 << 30);
      sc[j] = s; if (s > mloc) mloc = s;
    }
    int m = wave_reduce_max(mloc);
    int ssum = 0;
    #pragma unroll
    for (int j = 0; j < 16; j++) {
      int k = lane + j*64;
      int e = 0;
      if (k <= qi) {
        int sh = sc[j] - m;              // <= 0
        e = (sh >= -3) ? (256 + sh*64)
          : (sh >= -8) ? (64 + (sh + 3)*11)
          : (sh >= -24) ? (sh + 24) : 0;
      }
      sc[j] = e; ssum += e;
    }
    int s0 = wave_reduce_add(ssum); if (s0 < 1) s0 = 1;
    float sf = (float)s0;
    #pragma unroll
    for (int j = 0; j < 16; j++) {
      int k = lane + j*64;
      int p = (int)__builtin_rintf((float)sc[j] / sf * 255.0f);  // 0 for k>qi
      spb[k] = (uint8_t)clampi(p, 0, 255);
    }
    __builtin_amdgcn_s_waitcnt(WAIT_LGKM);   // wave-private row: ds writes -> reads
    // ---- PV via packed sdot4: p = 2*(p>>1) + (p&1) ----
    int hi0=0, hi1=0, hi2=0, hi3=0, lo0=0, lo1=0, lo2=0, lo3=0;
    int cmax = qi >> 2;
    for (int c = kc; c <= cmax; c += 8) {
      int p4 = spw[c];
      int ph = (p4 >> 1) & 0x7f7f7f7f;
      int pl = p4 & 0x01010101;
      int v0 = vr0[c], v1 = vr1[c], v2 = vr2[c], v3 = vr3[c];
      hi0 = sdot4(ph, v0, hi0); lo0 = sdot4(pl, v0, lo0);
      hi1 = sdot4(ph, v1, hi1); lo1 = sdot4(pl, v1, lo1);
      hi2 = sdot4(ph, v2, hi2); lo2 = sdot4(pl, v2, lo2);
      hi3 = sdot4(ph, v3, hi3); lo3 = sdot4(pl, v3, lo3);
    }
    int a0 = 2*hi0 + lo0, a1 = 2*hi1 + lo1, a2 = 2*hi2 + lo2, a3 = 2*hi3 + lo3;
    #pragma unroll
    for (int off = 8; off < 64; off <<= 1) {
      a0 += __shfl_xor(a0, off, 64);
      a1 += __shfl_xor(a1, off, 64);
      a2 += __shfl_xor(a2, off, 64);
      a3 += __shfl_xor(a3, off, 64);
    }
    if (kc == 0) {
      int r0 = wrap8(a0 >> 8) & 255;
      int r1 = wrap8(a1 >> 8) & 255;
      int r2 = wrap8(a2 >> 8) & 255;
      int r3 = wrap8(a3 >> 8) & 255;
      int packed = r0 | (r1 << 8) | (r2 << 16) | (r3 << 24);
      *(int*)(aOut + (b*T_CTX + qi)*DM + h*HD + dg*4) = packed;
    }
  }
}

// post-layer: o-proj + residual + FFN + residual, then QKV(L+1) or final norm. One token per wave.
__device__ __forceinline__ void post_phase(int t, int w, int lane, int L,
    int8_t* x, const int8_t* __restrict__ aArr,
    int8_t* qA, int8_t* kA, int8_t* vT,
    const int8_t* __restrict__ wt, const int16_t* __restrict__ gq,
    int8_t* xf, char* smemc)
{
  int8_t* myS = (int8_t*)smemc + w*DFF;
  const int8_t* wtL = wt + L*49152;
  int xv = (int)x[t*DM + lane];
  myS[lane] = aArr[t*DM + lane];
  __syncthreads();
  { // o-projection
    const int* a4 = (const int*)myS;
    const int* wo = (const int*)(wtL + 12288);
    int acc = 0;
    #pragma unroll
    for (int i = 0; i < 16; i++) acc = sdot4(a4[i], wo[lane*16 + i], acc);
    xv = wrap8(xv + clampi(acc >> 6, -128, 127));
  }
  __syncthreads();
  int h2 = rmsnorm_one(xv, (int)gq[(4 + L)*DM + lane]);
  myS[lane] = (int8_t)h2;
  __syncthreads();
  int uv[4];
  { // up projection (256 outs, 4/lane) + relu
    const int* h4 = (const int*)myS;
    const int* wu = (const int*)(wtL + 16384);
    #pragma unroll
    for (int jj = 0; jj < 4; jj++) {
      int acc = 0;
      #pragma unroll
      for (int i = 0; i < 16; i++) acc = sdot4(h4[i], wu[(jj*64 + lane)*16 + i], acc);
      int u = clampi(acc >> 6, -128, 127);
      uv[jj] = u < 0 ? 0 : u;
    }
  }
  __syncthreads();
  #pragma unroll
  for (int jj = 0; jj < 4; jj++) myS[jj*64 + lane] = (int8_t)uv[jj];
  __syncthreads();
  { // down projection
    const int* u4 = (const int*)myS;
    const int* wd = (const int*)(wtL + 32768);
    int acc = 0;
    #pragma unroll
    for (int i = 0; i < 64; i++) acc = sdot4(u4[i], wd[lane*64 + i], acc);
    xv = wrap8(xv + clampi(acc >> 6, -128, 127));
  }
  x[t*DM + lane] = (int8_t)xv;
  __syncthreads();
  if (L < 3) {
    do_qkv(t, xv, L + 1, lane, myS, wt, gq, qA, kA, vT);
  } else {
    int h = rmsnorm_one(xv, (int)gq[8*DM + lane]);
    xf[t*DM + lane] = (int8_t)h;
  }
}

// ---------------- megakernel: prep + embed + 4 layers; 1024 blocks @ 4/CU co-resident ----------------
__global__ __launch_bounds__(256, 4) void mega(
    const int* __restrict__ tokens, const float* __restrict__ tok_emb, const float* __restrict__ pos_emb,
    const float* __restrict__ anw, const float* __restrict__ qw, const float* __restrict__ kw,
    const float* __restrict__ vw, const float* __restrict__ ow, const float* __restrict__ fnw,
    const float* __restrict__ uw, const float* __restrict__ dw, const float* __restrict__ finw,
    int8_t* x, int8_t* a, int8_t* qA, int8_t* kA, int8_t* vT,
    int8_t* wt, int16_t* gq, int8_t* elo, int8_t* ehi, int8_t* xf,
    int* bar)
{
  __shared__ __align__(16) char smemc[36992];  // attn: V^T 32896 + probs 4096; token: 1KB; prep: 2KB
  int tid = threadIdx.x, bid = blockIdx.x;
  int w = tid >> 6, lane = tid & 63;
  int gw = bid*4 + w;                          // 0..4095 == token id

  // ---- P0: weight ternarize + gammas + emb split + embed ----
  if (bid < 24) {
    int layer = bid / 6, kind = bid % 6;
    const float* src; int n; int off;
    switch (kind) {
      case 0:  src = qw + layer*4096;  n = 4096;  off = 0;     break;
      case 1:  src = kw + layer*4096;  n = 4096;  off = 4096;  break;
      case 2:  src = vw + layer*4096;  n = 4096;  off = 8192;  break;
      case 3:  src = ow + layer*4096;  n = 4096;  off = 12288; break;
      case 4:  src = uw + layer*16384; n = 16384; off = 16384; break;
      default: src = dw + layer*16384; n = 16384; off = 32768; break;
    }
    double* sred = (double*)smemc;
    double s = 0.0;
    for (int i = tid; i < n; i += 256) s += (double)__builtin_fabsf(src[i]);
    sred[tid] = s; __syncthreads();
    for (int st = 128; st > 0; st >>= 1){ if (tid < st) sred[tid] += sred[tid + st]; __syncthreads(); }
    float fs = (float)(sred[0] / (double)n);
    if (fs < 1e-5f) fs = 1e-5f;
    int8_t* dst = wt + layer*49152 + off;
    for (int i = tid; i < n; i += 256) {
      int tq = (int)__builtin_rintf(src[i] / fs);
      dst[i] = (int8_t)clampi(tq, -1, 1);
    }
  } else if (bid == 24) {
    for (int i = tid; i < 576; i += 256) {
      int norm = i >> 6, c = i & 63;
      const float* wsrc = (norm < 4) ? (anw + norm*64) : (norm < 8) ? (fnw + (norm-4)*64) : finw;
      float wv = wsrc[c];
      float wc = wv < -2.0f ? -2.0f : (wv > 2.0f ? 2.0f : wv);
      gq[i] = (int16_t)clampi((int)__builtin_rintf(wc * 1024.0f), -32768, 32767);
    }
  }
  for (int i = bid*256 + tid; i < NVOCAB*DM; i += NBLOCKS*256) {
    int e  = clampi((int)__builtin_rintf(tok_emb[i] * 1024.0f), -32768, 32767);
    int l  = ((e + 128) & 255) - 128;
    int hh = (e - l) >> 8;
    if (hh > 127) hh = 127;
    elo[i] = (int8_t)l; ehi[i] = (int8_t)hh;
  }
  for (int i = bid*256 + tid; i < 4096*DM; i += NBLOCKS*256) {
    int t = i >> 6, c = i & 63;
    int tok = tokens[t];
    int s = t & (T_CTX - 1);
    int tq = clampi((int)__builtin_rintf(tok_emb[tok*DM + c] * 1024.0f), -32768, 32767);
    int pq = clampi((int)__builtin_rintf(pos_emb[s*DM + c] * 1024.0f), -32768, 32767);
    x[i] = (int8_t)wrap8((tq + pq) >> 3);
  }
  gbar(bar, bid);

  // ---- QKV for layer 0 (one token per wave) ----
  {
    int8_t* myS = (int8_t*)smemc + w*DFF;
    int xv = (int)x[gw*DM + lane];
    do_qkv(gw, xv, 0, lane, myS, wt, gq, qA, kA, vT);
  }
  gbar(bar, bid);

  // ---- 4 layers ----
  for (int L = 0; L < 4; L++) {
    attn_phase(bid, w, lane, qA, kA, vT, a, smemc);
    gbar(bar, bid);
    post_phase(gw, w, lane, L, x, a, qA, kA, vT, wt, gq, xf, smemc);
    if (L < 3) gbar(bar, bid);
  }
}

// ---------------- logits: xf[4096x64] int8 x emb(hi/lo int8)[8192x64]^T via i8 MFMA ----------------
__global__ __launch_bounds__(256) void logits_kernel(
    const int8_t* __restrict__ xf, const int8_t* __restrict__ elo, const int8_t* __restrict__ ehi,
    float* __restrict__ out)
{
  int w = threadIdx.x >> 6, lane = threadIdx.x & 63;
  int m = lane & 15, quad = lane >> 4;
  int tokBase = blockIdx.y * 64 + w * 16;
  v4i A = *(const v4i*)(xf + (tokBase + m)*DM + quad*16);  // A[m=lane&15][k=quad*16+j]
  #pragma unroll
  for (int tile = 0; tile < 8; tile++) {
    int vocBase = blockIdx.x * 128 + tile * 16;
    v4i Blo = *(const v4i*)(elo + (vocBase + m)*DM + quad*16);
    v4i Bhi = *(const v4i*)(ehi + (vocBase + m)*DM + quad*16);
    v4i zero = {0, 0, 0, 0};
    v4i dLo = __builtin_amdgcn_mfma_i32_16x16x64_i8(A, Blo, zero, 0, 0, 0);
    v4i dHi = __builtin_amdgcn_mfma_i32_16x16x64_i8(A, Bhi, zero, 0, 0, 0);
    #pragma unroll
    for (int r = 0; r < 4; r++) {
      int val = dLo[r] + (dHi[r] << 8);                     // dot(x, 256*hi + lo), exact int32
      int row = tokBase + quad*4 + r;                       // C/D: row=(lane>>4)*4+reg
      int col = vocBase + m;                                // col=lane&15
      out[row*NVOCAB + col] = (float)val * 1.220703125e-4f; // * 2^-13 == D^-0.5/1024
    }
  }
}

extern "C" void kernel_launch(void* const* d_in, const int* in_sizes, int n_in,
                              void* d_out, int out_size, void* d_ws, size_t ws_size,
                              hipStream_t stream)
{
  const int*   tokens  = (const int*)d_in[0];
  const float* tok_emb = (const float*)d_in[1];
  const float* pos_emb = (const float*)d_in[2];
  const float* attn_nw = (const float*)d_in[3];
  const float* q_w     = (const float*)d_in[4];
  const float* k_w     = (const float*)d_in[5];
  const float* v_w     = (const float*)d_in[6];
  const float* o_w     = (const float*)d_in[7];
  const float* ff_nw   = (const float*)d_in[8];
  const float* up_w    = (const float*)d_in[9];
  const float* dn_w    = (const float*)d_in[10];
  const float* fin_nw  = (const float*)d_in[11];
  float* out = (float*)d_out;
  char* ws = (char*)d_ws;

  int8_t*  x   = (int8_t*)(ws + 0);        // 4096*64
  int8_t*  a   = (int8_t*)(ws + 262144);   // 4096*64 attn output (token-major)
  int8_t*  qA  = (int8_t*)(ws + 524288);   // [b][h][t][d]
  int8_t*  kA  = (int8_t*)(ws + 786432);   // [b][h][t][d]
  int8_t*  vT  = (int8_t*)(ws + 1048576);  // [b][h][d][t]  (transposed V)
  int8_t*  wt  = (int8_t*)(ws + 1310720);  // 4 layers * 49152 ternary weights
  int8_t*  elo = (int8_t*)(ws + 1507328);  // 8192*64
  int8_t*  ehi = (int8_t*)(ws + 2031616);  // 8192*64
  int16_t* gq  = (int16_t*)(ws + 2555904); // 9*64
  int8_t*  xf  = (int8_t*)(ws + 2560000);  // 4096*64
  int*     bar = (int*)(ws + 2822144);     // 8 group lines + master + gen (2KB)

  hipMemsetAsync(bar, 0, 2048, stream);
  mega<<<NBLOCKS, 256, 0, stream>>>(
      tokens, tok_emb, pos_emb, attn_nw, q_w, k_w, v_w, o_w, ff_nw, up_w, dn_w, fin_nw,
      x, a, qA, kA, vT, wt, gq, elo, ehi, xf, bar);
  logits_kernel<<<dim3(64, 64), 256, 0, stream>>>(xf, elo, ehi, out);
}

// Round 6
// 539.335 us; speedup vs baseline: 1.9195x; 1.4623x over previous
//
#include <hip/hip_runtime.h>
#include <stdint.h>

#define T_CTX 1024
#define DM 64
#define NH 2
#define HD 32
#define DFF 256
#define NVOCAB 8192
#define WAIT_LGKM 0xC07F   // s_waitcnt lgkmcnt(0)

typedef int v4i __attribute__((ext_vector_type(4)));

__device__ __forceinline__ int clampi(int v, int lo, int hi){ return v<lo?lo:(v>hi?hi:v); }
__device__ __forceinline__ int wrap8(int v){ return ((v + 128) & 255) - 128; }
__device__ __forceinline__ int sdot4(int a, int b, int c){ return __builtin_amdgcn_sdot4(a, b, c, false); }

__device__ __forceinline__ int wave_reduce_add(int v){
  #pragma unroll
  for (int off = 1; off < 64; off <<= 1) v += __shfl_xor(v, off, 64);
  return v;
}
__device__ __forceinline__ int wave_reduce_max(int v){
  #pragma unroll
  for (int off = 1; off < 64; off <<= 1){ int o = __shfl_xor(v, off, 64); v = o > v ? o : v; }
  return v;
}

// rmsnorm_hw forward: exact integer pipeline; lane == channel (wave64 == DM)
__device__ __forceinline__ int rmsnorm_one(int xv, int g){
  int ss  = wave_reduce_add(xv * xv);
  int ms  = ss >> 6;                 // /64 == /d_model
  int lut = ms >> 6; if (lut > 255) lut = 255;
  int bc  = lut * 64 + 32;           // >= 32, so max(.,1) vacuous
  int inv = (int)__builtin_rint(16384.0 / __builtin_sqrt((double)bc)); // <= 2897 < 16383
  int p1  = (xv * inv) >> 8;         // arithmetic shift == floor
  int y   = (p1 * g) >> 10;
  return clampi(y, -128, 127);
}

// norm + QKV projections for one token; myS = wave-private 256B LDS (lgkm sync only).
// V written transposed: vT[bh][d][t].
__device__ __forceinline__ void do_qkv(int t, int xv, int L, int lane, int8_t* myS,
    const int8_t* wt, const int16_t* gq, int8_t* qA, int8_t* kA, int8_t* vT)
{
  int h = rmsnorm_one(xv, (int)gq[L*DM + lane]);
  myS[lane] = (int8_t)h;
  __builtin_amdgcn_s_waitcnt(WAIT_LGKM);
  const int8_t* wtL = wt + L*49152;
  const int* h4 = (const int*)myS;
  const int* wq = (const int*)(wtL + 0);
  const int* wk = (const int*)(wtL + 4096);
  const int* wv = (const int*)(wtL + 8192);
  int b = t >> 10, s = t & (T_CTX - 1);
  int hh = lane >> 5, d = lane & 31;
  int bhh = b*NH + hh;
  int accq = 0, acck = 0, accv = 0;
  #pragma unroll
  for (int i = 0; i < 16; i++) {
    int hv = h4[i];
    accq = sdot4(hv, wq[lane*16 + i], accq);
    acck = sdot4(hv, wk[lane*16 + i], acck);
    accv = sdot4(hv, wv[lane*16 + i], accv);
  }
  qA[(bhh*T_CTX + s)*HD + d] = (int8_t)clampi(accq >> 6, -128, 127);
  kA[(bhh*T_CTX + s)*HD + d] = (int8_t)clampi(acck >> 6, -128, 127);
  vT[(bhh*HD + d)*T_CTX + s] = (int8_t)clampi(accv >> 6, -128, 127);
}

// ---------------- K1: ternarize weights + quantize norm gammas ----------------
__global__ __launch_bounds__(256) void prep_weights(
    const float* __restrict__ qw, const float* __restrict__ kw, const float* __restrict__ vw,
    const float* __restrict__ ow, const float* __restrict__ uw, const float* __restrict__ dw,
    const float* __restrict__ anw, const float* __restrict__ fnw, const float* __restrict__ finw,
    int8_t* __restrict__ wt, int16_t* __restrict__ gq)
{
  int tid = threadIdx.x;
  int bid = blockIdx.x;
  if (bid < 24) {
    int layer = bid / 6, kind = bid % 6;
    const float* src; int n; int off;
    switch (kind) {
      case 0:  src = qw + layer*4096;  n = 4096;  off = 0;     break;
      case 1:  src = kw + layer*4096;  n = 4096;  off = 4096;  break;
      case 2:  src = vw + layer*4096;  n = 4096;  off = 8192;  break;
      case 3:  src = ow + layer*4096;  n = 4096;  off = 12288; break;
      case 4:  src = uw + layer*16384; n = 16384; off = 16384; break;
      default: src = dw + layer*16384; n = 16384; off = 32768; break;
    }
    __shared__ double sred[256];
    double s = 0.0;
    for (int i = tid; i < n; i += 256) s += (double)__builtin_fabsf(src[i]);
    sred[tid] = s; __syncthreads();
    for (int st = 128; st > 0; st >>= 1){ if (tid < st) sred[tid] += sred[tid + st]; __syncthreads(); }
    float fs = (float)(sred[0] / (double)n);
    if (fs < 1e-5f) fs = 1e-5f;
    int8_t* dst = wt + layer*49152 + off;
    for (int i = tid; i < n; i += 256) {
      int t = (int)__builtin_rintf(src[i] / fs);
      dst[i] = (int8_t)clampi(t, -1, 1);
    }
  } else {
    for (int i = tid; i < 576; i += 256) {
      int norm = i >> 6, c = i & 63;
      const float* wsrc = (norm < 4) ? (anw + norm*64) : (norm < 8) ? (fnw + (norm-4)*64) : finw;
      float wv = wsrc[c];
      float wc = wv < -2.0f ? -2.0f : (wv > 2.0f ? 2.0f : wv);
      gq[i] = (int16_t)clampi((int)__builtin_rintf(wc * 1024.0f), -32768, 32767);
    }
  }
}

// ---------------- K2: embed + QKV layer 0 (one token per wave) ----------------
__global__ __launch_bounds__(256, 4) void embed_qkv0(
    const int* __restrict__ tokens, const float* __restrict__ tok_emb, const float* __restrict__ pos_emb,
    int8_t* __restrict__ x, int8_t* __restrict__ qA, int8_t* __restrict__ kA, int8_t* __restrict__ vT,
    const int8_t* __restrict__ wt, const int16_t* __restrict__ gq)
{
  __shared__ __align__(16) int8_t sh8[4][DFF];
  int w = threadIdx.x >> 6, lane = threadIdx.x & 63;
  int t = blockIdx.x * 4 + w;
  int tok = tokens[t];
  int s = t & (T_CTX - 1);
  int tq = clampi((int)__builtin_rintf(tok_emb[tok*DM + lane] * 1024.0f), -32768, 32767);
  int pq = clampi((int)__builtin_rintf(pos_emb[s*DM + lane] * 1024.0f), -32768, 32767);
  int xv = wrap8((tq + pq) >> 3);
  x[t*DM + lane] = (int8_t)xv;
  do_qkv(t, xv, 0, lane, sh8[w], wt, gq, qA, kA, vT);
}

// ---------------- K3..K6: fused layer kernel ----------------
// Block = (batch b, 4 consecutive positions). Wave w: both attention rows of its
// token (h=0,1) -> a held in wave-private LDS -> o-proj + residual + FFN + residual
// -> QKV(L+1) into the OTHER qkv buffer set (or final norm at L==3). No global `a`,
// no grid barrier, no cross-block dependency inside the kernel.
__global__ __launch_bounds__(256, 4) void layer_kernel(
    const float* __restrict__ tok_emb,
    int8_t* __restrict__ x,
    const int8_t* __restrict__ qIn, const int8_t* __restrict__ kIn, const int8_t* __restrict__ vIn,
    int8_t* __restrict__ qOut, int8_t* __restrict__ kOut, int8_t* __restrict__ vOut,
    const int8_t* __restrict__ wt, const int16_t* __restrict__ gq,
    int8_t* __restrict__ elo, int8_t* __restrict__ ehi, int8_t* __restrict__ xf, int L)
{
  __shared__ __align__(16) char smemc[4096 + 256 + 1024]; // probs[4][1024] + a_buf[4][64] + myS[4][256]
  int tid = threadIdx.x, bid = blockIdx.x;
  int w = tid >> 6, lane = tid & 63;
  int b = bid >> 8, s = (bid & 255) * 4 + w;
  int t = b*T_CTX + s;

  if (L == 3) {
    // emb hi/lo split for logits (independent elementwise work, 2 els/thread)
    for (int i = bid*256 + tid; i < NVOCAB*DM; i += 1024*256) {
      int e  = clampi((int)__builtin_rintf(tok_emb[i] * 1024.0f), -32768, 32767);
      int l  = ((e + 128) & 255) - 128;
      int hh = (e - l) >> 8;
      if (hh > 127) hh = 127;
      elo[i] = (int8_t)l; ehi[i] = (int8_t)hh;
    }
  }

  uint8_t* spb = (uint8_t*)(smemc + w*1024);           // wave-private prob row
  const int* spw = (const int*)spb;
  int8_t* a_buf = (int8_t*)(smemc + 4096 + w*64);      // wave-private attn output
  int8_t* myS   = (int8_t*)(smemc + 4096 + 256 + w*DFF);

  int qi = s;
  int dg = lane & 7, kc = lane >> 3;

  // ---- attention: both heads of this wave's token ----
  for (int h = 0; h < 2; h++) {
    int bh = b*NH + h;
    const int8_t* qBase = qIn + bh*(T_CTX*HD);
    const int8_t* kBase = kIn + bh*(T_CTX*HD);
    const int4* qr = (const int4*)(qBase + qi*HD);
    int4 qa = qr[0], qb = qr[1];
    int sc[16];
    int mloc = -(1 << 30);
    #pragma unroll
    for (int j = 0; j < 16; j++) {
      int k = lane + j*64;
      int sv;
      if (k <= qi) {
        const int4* kr = (const int4*)(kBase + k*HD);
        int4 ka = kr[0], kb = kr[1];
        int d0 = 0, d1 = 0;
        d0 = sdot4(qa.x, ka.x, d0); d1 = sdot4(qa.y, ka.y, d1);
        d0 = sdot4(qa.z, ka.z, d0); d1 = sdot4(qa.w, ka.w, d1);
        d0 = sdot4(qb.x, kb.x, d0); d1 = sdot4(qb.y, kb.y, d1);
        d0 = sdot4(qb.z, kb.z, d0); d1 = sdot4(qb.w, kb.w, d1);
        sv = ((d0 + d1) * 45) >> 8;      // floor; diag >=0 so the -32767 mask never wins max
      } else sv = -(1 << 30);
      sc[j] = sv; if (sv > mloc) mloc = sv;
    }
    int m = wave_reduce_max(mloc);
    int ssum = 0;
    #pragma unroll
    for (int j = 0; j < 16; j++) {
      int k = lane + j*64;
      int e = 0;
      if (k <= qi) {
        int sh = sc[j] - m;              // <= 0
        e = (sh >= -3) ? (256 + sh*64)
          : (sh >= -8) ? (64 + (sh + 3)*11)
          : (sh >= -24) ? (sh + 24) : 0;
      }
      sc[j] = e; ssum += e;
    }
    int s0 = wave_reduce_add(ssum); if (s0 < 1) s0 = 1;
    float sf = (float)s0;
    #pragma unroll
    for (int j = 0; j < 16; j++) {
      int k = lane + j*64;
      int p = (int)__builtin_rintf((float)sc[j] / sf * 255.0f);  // 0 for k>qi
      spb[k] = (uint8_t)clampi(p, 0, 255);
    }
    __builtin_amdgcn_s_waitcnt(WAIT_LGKM);   // wave-private row: ds writes -> reads
    // PV via packed sdot4 (p = 2*(p>>1) + (p&1)); V^T rows read from global (L2)
    const int* vr0 = (const int*)(vIn + (bh*HD + dg*4 + 0)*T_CTX);
    const int* vr1 = (const int*)(vIn + (bh*HD + dg*4 + 1)*T_CTX);
    const int* vr2 = (const int*)(vIn + (bh*HD + dg*4 + 2)*T_CTX);
    const int* vr3 = (const int*)(vIn + (bh*HD + dg*4 + 3)*T_CTX);
    int hi0=0, hi1=0, hi2=0, hi3=0, lo0=0, lo1=0, lo2=0, lo3=0;
    int cmax = qi >> 2;
    for (int c = kc; c <= cmax; c += 8) {
      int p4 = spw[c];
      int ph = (p4 >> 1) & 0x7f7f7f7f;
      int pl = p4 & 0x01010101;
      int v0 = vr0[c], v1 = vr1[c], v2 = vr2[c], v3 = vr3[c];
      hi0 = sdot4(ph, v0, hi0); lo0 = sdot4(pl, v0, lo0);
      hi1 = sdot4(ph, v1, hi1); lo1 = sdot4(pl, v1, lo1);
      hi2 = sdot4(ph, v2, hi2); lo2 = sdot4(pl, v2, lo2);
      hi3 = sdot4(ph, v3, hi3); lo3 = sdot4(pl, v3, lo3);
    }
    int a0 = 2*hi0 + lo0, a1 = 2*hi1 + lo1, a2 = 2*hi2 + lo2, a3 = 2*hi3 + lo3;
    #pragma unroll
    for (int off = 8; off < 64; off <<= 1) {
      a0 += __shfl_xor(a0, off, 64);
      a1 += __shfl_xor(a1, off, 64);
      a2 += __shfl_xor(a2, off, 64);
      a3 += __shfl_xor(a3, off, 64);
    }
    if (kc == 0) {
      int r0 = wrap8(a0 >> 8) & 255;
      int r1 = wrap8(a1 >> 8) & 255;
      int r2 = wrap8(a2 >> 8) & 255;
      int r3 = wrap8(a3 >> 8) & 255;
      int packed = r0 | (r1 << 8) | (r2 << 16) | (r3 << 24);
      *(int*)(a_buf + h*HD + dg*4) = packed;   // LDS, wave-private
    }
  }
  __builtin_amdgcn_s_waitcnt(WAIT_LGKM);       // a_buf writes -> post reads

  // ---- post: o-proj + residual + FFN + residual ----
  const int8_t* wtL = wt + L*49152;
  int xv = (int)x[t*DM + lane];
  { // o-projection from LDS a_buf
    const int* a4 = (const int*)a_buf;
    const int* wo = (const int*)(wtL + 12288);
    int acc = 0;
    #pragma unroll
    for (int i = 0; i < 16; i++) acc = sdot4(a4[i], wo[lane*16 + i], acc);
    xv = wrap8(xv + clampi(acc >> 6, -128, 127));
  }
  int h2 = rmsnorm_one(xv, (int)gq[(4 + L)*DM + lane]);
  myS[lane] = (int8_t)h2;
  __builtin_amdgcn_s_waitcnt(WAIT_LGKM);
  int uv[4];
  { // up projection (256 outs, 4/lane) + relu
    const int* h4 = (const int*)myS;
    const int* wu = (const int*)(wtL + 16384);
    #pragma unroll
    for (int jj = 0; jj < 4; jj++) {
      int acc = 0;
      #pragma unroll
      for (int i = 0; i < 16; i++) acc = sdot4(h4[i], wu[(jj*64 + lane)*16 + i], acc);
      int u = clampi(acc >> 6, -128, 127);
      uv[jj] = u < 0 ? 0 : u;
    }
  }
  #pragma unroll
  for (int jj = 0; jj < 4; jj++) myS[jj*64 + lane] = (int8_t)uv[jj];
  __builtin_amdgcn_s_waitcnt(WAIT_LGKM);
  { // down projection
    const int* u4 = (const int*)myS;
    const int* wd = (const int*)(wtL + 32768);
    int acc = 0;
    #pragma unroll
    for (int i = 0; i < 64; i++) acc = sdot4(u4[i], wd[lane*64 + i], acc);
    xv = wrap8(xv + clampi(acc >> 6, -128, 127));
  }
  x[t*DM + lane] = (int8_t)xv;
  if (L < 3) {
    do_qkv(t, xv, L + 1, lane, myS, wt, gq, qOut, kOut, vOut);
  } else {
    int h = rmsnorm_one(xv, (int)gq[8*DM + lane]);
    xf[t*DM + lane] = (int8_t)h;
  }
}

// ---------------- K7: logits via i8 MFMA (hi/lo int8 planes of Q5.10 emb) ----------------
__global__ __launch_bounds__(256) void logits_kernel(
    const int8_t* __restrict__ xf, const int8_t* __restrict__ elo, const int8_t* __restrict__ ehi,
    float* __restrict__ out)
{
  int w = threadIdx.x >> 6, lane = threadIdx.x & 63;
  int m = lane & 15, quad = lane >> 4;
  int tokBase = blockIdx.y * 64 + w * 16;
  v4i A = *(const v4i*)(xf + (tokBase + m)*DM + quad*16);  // A[m=lane&15][k=quad*16+j]
  #pragma unroll
  for (int tile = 0; tile < 8; tile++) {
    int vocBase = blockIdx.x * 128 + tile * 16;
    v4i Blo = *(const v4i*)(elo + (vocBase + m)*DM + quad*16);
    v4i Bhi = *(const v4i*)(ehi + (vocBase + m)*DM + quad*16);
    v4i zero = {0, 0, 0, 0};
    v4i dLo = __builtin_amdgcn_mfma_i32_16x16x64_i8(A, Blo, zero, 0, 0, 0);
    v4i dHi = __builtin_amdgcn_mfma_i32_16x16x64_i8(A, Bhi, zero, 0, 0, 0);
    #pragma unroll
    for (int r = 0; r < 4; r++) {
      int val = dLo[r] + (dHi[r] << 8);                     // dot(x, 256*hi + lo), exact int32
      int row = tokBase + quad*4 + r;                       // C/D: row=(lane>>4)*4+reg
      int col = vocBase + m;                                // col=lane&15
      out[row*NVOCAB + col] = (float)val * 1.220703125e-4f; // * 2^-13 == D^-0.5/1024
    }
  }
}

extern "C" void kernel_launch(void* const* d_in, const int* in_sizes, int n_in,
                              void* d_out, int out_size, void* d_ws, size_t ws_size,
                              hipStream_t stream)
{
  const int*   tokens  = (const int*)d_in[0];
  const float* tok_emb = (const float*)d_in[1];
  const float* pos_emb = (const float*)d_in[2];
  const float* attn_nw = (const float*)d_in[3];
  const float* q_w     = (const float*)d_in[4];
  const float* k_w     = (const float*)d_in[5];
  const float* v_w     = (const float*)d_in[6];
  const float* o_w     = (const float*)d_in[7];
  const float* ff_nw   = (const float*)d_in[8];
  const float* up_w    = (const float*)d_in[9];
  const float* dn_w    = (const float*)d_in[10];
  const float* fin_nw  = (const float*)d_in[11];
  float* out = (float*)d_out;
  char* ws = (char*)d_ws;

  int8_t*  x   = (int8_t*)(ws + 0);        // 4096*64
  int8_t*  qA0 = (int8_t*)(ws + 262144);   // qkv set 0 (even layers' input)
  int8_t*  kA0 = (int8_t*)(ws + 524288);
  int8_t*  vA0 = (int8_t*)(ws + 786432);
  int8_t*  qA1 = (int8_t*)(ws + 1048576);  // qkv set 1 (odd layers' input)
  int8_t*  kA1 = (int8_t*)(ws + 1310720);
  int8_t*  vA1 = (int8_t*)(ws + 1572864);
  int8_t*  wt  = (int8_t*)(ws + 1835008);  // 4 layers * 49152 ternary weights
  int8_t*  elo = (int8_t*)(ws + 2031616);  // 8192*64
  int8_t*  ehi = (int8_t*)(ws + 2555904);  // 8192*64
  int16_t* gq  = (int16_t*)(ws + 3080192); // 9*64
  int8_t*  xf  = (int8_t*)(ws + 3082240);  // 4096*64

  prep_weights<<<25, 256, 0, stream>>>(q_w, k_w, v_w, o_w, up_w, dn_w, attn_nw, ff_nw, fin_nw, wt, gq);
  embed_qkv0<<<1024, 256, 0, stream>>>(tokens, tok_emb, pos_emb, x, qA0, kA0, vA0, wt, gq);
  layer_kernel<<<1024, 256, 0, stream>>>(tok_emb, x, qA0, kA0, vA0, qA1, kA1, vA1, wt, gq, elo, ehi, xf, 0);
  layer_kernel<<<1024, 256, 0, stream>>>(tok_emb, x, qA1, kA1, vA1, qA0, kA0, vA0, wt, gq, elo, ehi, xf, 1);
  layer_kernel<<<1024, 256, 0, stream>>>(tok_emb, x, qA0, kA0, vA0, qA1, kA1, vA1, wt, gq, elo, ehi, xf, 2);
  layer_kernel<<<1024, 256, 0, stream>>>(tok_emb, x, qA1, kA1, vA1, qA0, kA0, vA0, wt, gq, elo, ehi, xf, 3);
  logits_kernel<<<dim3(64, 64), 256, 0, stream>>>(xf, elo, ehi, out);
}